// Round 4
// baseline (470.201 us; speedup 1.0000x reference)
//
#include <hip/hip_runtime.h>
#include <hip/hip_fp16.h>

// GAT layer (2 heads, N=100k, D=64, E=1.7M), fp32.
// R4 REDESIGN: the R0-R3 pipeline spent ~130us in a 4-kernel LDS counting-sort
// (hist/col_scan/binning/rowsort) whose only product was contiguous per-node
// edge runs, while the gather it fed cost ~50us. Replaced with global-atomic
// bucketing (~5M fire-and-forget L2 atomics + 1.7M returning) which produces
// the SAME contiguous (col,coef) runs AND precombines the softmax coef per
// edge, deleting the gather's whole phase-1 (exp/rowsum/stash serial dep).
//   k_scores : blocks [0,ZBLK) zero rowsum+cnt; rest: f16 cast of x + 4 dots
//   k_edge1  : per edge e0,e1 = exp(leaky(score)); atomicAdd rowsums + count
//   k_scan_a : 256-chunk local excl scan of counts -> offs, chunk totals ->
//              bsum; invrs[n] = 0.5/rowsum
//   k_scan_b : 1-block excl scan of bsum (chunk bases)
//   k_edge2  : recompute e0,e1; coef = e0*inv0+e1*inv1; p=atomicAdd(offs[r]);
//              pairs[bsum[r>>8]+p] = (col, coef)   [8B scatter, L2-absorbed]
//   k_gather : 1 wave/node, 2 half-waves x 2 edges/iter, f16 dword loads
//              (cvt_f32_f16 feeds FMA directly - no unpack VALU)
// out[i,:] = sum_e coef[e]*x[col[e],:]; convex combo per head -> f16 storage
// err <= max|x|*2^-11 (~8x tighter than the old bf16 path's 0.0078).
// Nondeterminism: pair order within a run + atomic rowsum order reorder fp32
// sums only (~1e-6 noise, far inside tolerance). Workspace ~30.4 MB (~= old).
// NOTE: xh stays 128B-row-aligned (256B-aligned alloc) - R4 lesson upheld.

#define D 64
#define ALPHA 0.2f

// fused: blocks [0,ZBLK) zero the rowsum+cnt region (int4 stores);
//        blocks [ZBLK,..) one wave per node: f16 cast + 4 length-64 dots
__global__ __launch_bounds__(256) void k_scores(
    const float* __restrict__ x, const float* __restrict__ W,
    const float* __restrict__ a, float2* __restrict__ ssrc,
    float2* __restrict__ sdst, __half* __restrict__ xh,
    int4* __restrict__ zero4, int zwords4, int ZBLK, int N)
{
    if ((int)blockIdx.x < ZBLK) {
        int i = blockIdx.x * 256 + threadIdx.x;
        if (i < zwords4) zero4[i] = make_int4(0, 0, 0, 0);
        return;
    }
    int wid  = (blockIdx.x - ZBLK) * 4 + (threadIdx.x >> 6);
    int lane = threadIdx.x & 63;
    if (wid >= N) return;
    float v = x[(size_t)wid * D + lane];
    xh[(size_t)wid * D + lane] = __float2half(v);   // |x| <= ~5.5, f16-safe
    float h0 = v * W[lane];
    float h1 = v * W[D + lane];
    float t0 = h0 * a[lane];          // src head0
    float t1 = h0 * a[D + lane];      // dst head0
    float t2 = h1 * a[2 * D + lane];  // src head1
    float t3 = h1 * a[3 * D + lane];  // dst head1
#pragma unroll
    for (int off = 32; off; off >>= 1) {
        t0 += __shfl_xor(t0, off);
        t1 += __shfl_xor(t1, off);
        t2 += __shfl_xor(t2, off);
        t3 += __shfl_xor(t3, off);
    }
    if (lane == 0) { ssrc[wid] = make_float2(t0, t2); sdst[wid] = make_float2(t1, t3); }
}

// per edge: e-values -> atomic rowsums (fire-and-forget f32) + atomic count
__global__ __launch_bounds__(256) void k_edge1(
    const int* __restrict__ row, const int* __restrict__ col,
    const float2* __restrict__ ssrc, const float2* __restrict__ sdst,
    float* __restrict__ rowsum, int* __restrict__ cnt, int E)
{
    int i = blockIdx.x * 256 + threadIdx.x;
    if (i >= E) return;
    int r = row[i], c = col[i];
    float2 sa = ssrc[r], sb = sdst[c];
    float sc0 = sa.x + sb.x, sc1 = sa.y + sb.y;
    float e0 = __expf(sc0 > 0.f ? sc0 : ALPHA * sc0);
    float e1 = __expf(sc1 > 0.f ? sc1 : ALPHA * sc1);
    atomicAdd(&rowsum[2 * r],     e0);
    atomicAdd(&rowsum[2 * r + 1], e1);
    atomicAdd(&cnt[r], 1);
}

// per 256-node chunk: local exclusive scan of counts -> offs, total -> bsum;
// also invrs[n] = 0.5/rowsum[n] (amortizes the division per node, not edge)
__global__ __launch_bounds__(256) void k_scan_a(
    const int* __restrict__ cnt, const float2* __restrict__ rowsum2,
    int* __restrict__ offs, int* __restrict__ bsum,
    float2* __restrict__ invrs)
{
    __shared__ int ws[256];
    int b = blockIdx.x, t = threadIdx.x;
    int i = b * 256 + t;                 // grid covers NPAD (pad counts = 0)
    int v = cnt[i];
    ws[t] = v;
    __syncthreads();
    for (int off = 1; off < 256; off <<= 1) {
        int add = (t >= off) ? ws[t - off] : 0;
        __syncthreads();
        ws[t] += add;
        __syncthreads();
    }
    offs[i] = ws[t] - v;                 // local exclusive
    if (t == 255) bsum[b] = ws[255];
    float2 rs = rowsum2[i];              // pad rows: 0.5/0=inf, never consumed
    invrs[i] = make_float2(0.5f / rs.x, 0.5f / rs.y);
}

// single block: exclusive scan of chunk totals (nb <= 512)
__global__ __launch_bounds__(512) void k_scan_b(int* __restrict__ bsum, int nb)
{
    __shared__ int ws[512];
    int t = threadIdx.x;
    int v = (t < nb) ? bsum[t] : 0;
    ws[t] = v;
    __syncthreads();
    for (int off = 1; off < 512; off <<= 1) {
        int add = (t >= off) ? ws[t - off] : 0;
        __syncthreads();
        ws[t] += add;
        __syncthreads();
    }
    if (t < nb) bsum[t] = ws[t] - v;
}

// per edge: recompute e (cheaper than a 6.8MB eh buffer), precombine coef,
// claim slot via returning atomic, scatter (col,coef) into the node's run
__global__ __launch_bounds__(256) void k_edge2(
    const int* __restrict__ row, const int* __restrict__ col,
    const float2* __restrict__ ssrc, const float2* __restrict__ sdst,
    const float2* __restrict__ invrs, const int* __restrict__ bsum,
    int* __restrict__ offs, float2* __restrict__ pairs, int E)
{
    int i = blockIdx.x * 256 + threadIdx.x;
    if (i >= E) return;
    int r = row[i], c = col[i];
    float2 sa = ssrc[r], sb = sdst[c];
    float sc0 = sa.x + sb.x, sc1 = sa.y + sb.y;
    float e0 = __expf(sc0 > 0.f ? sc0 : ALPHA * sc0);
    float e1 = __expf(sc1 > 0.f ? sc1 : ALPHA * sc1);
    float2 iv = invrs[r];
    float cf = e0 * iv.x + e1 * iv.y;
    int p = atomicAdd(&offs[r], 1);      // offs becomes end-offset after pass
    pairs[bsum[r >> 8] + p] = make_float2(__int_as_float(c), cf);
}

// 4 nodes/block, 1 wave/node, NO phase-1: pure weighted row-sum.
// half = lane>>5 picks even/odd edge; lane&31 = feature dword (2 f16).
// 2 independent pair->row load chains per iter; high occupancy (no LDS,
// ~24 VGPR) gives the TLP that R1-R3's serial-dep structure never had.
__global__ __launch_bounds__(256) void k_gather(
    const unsigned* __restrict__ xhd, const float2* __restrict__ pairs,
    const int* __restrict__ offs, const int* __restrict__ cnt,
    const int* __restrict__ bsum, float* __restrict__ out, int N)
{
    int w    = threadIdx.x >> 6;
    int lane = threadIdx.x & 63;
    int n    = blockIdx.x * 4 + w;
    if (n >= N) return;                    // wave-uniform
    int cl    = cnt[n];                    // >= 1 (self-loops guaranteed)
    int start = bsum[n >> 8] + offs[n] - cl;   // offs[n] is now end-local
    int half  = lane >> 5;
    int li    = lane & 31;
    float acc0 = 0.f, acc1 = 0.f;
    for (int k = 0; k < cl; k += 4) {
        int j0 = k + half, j1 = k + 2 + half;
        float2 p0 = pairs[start + (j0 < cl ? j0 : cl - 1)];
        float2 p1 = pairs[start + (j1 < cl ? j1 : cl - 1)];
        float cf0 = (j0 < cl) ? p0.y : 0.f;
        float cf1 = (j1 < cl) ? p1.y : 0.f;
        unsigned u0 = xhd[((unsigned)__float_as_int(p0.x) << 5) + li];
        unsigned u1 = xhd[((unsigned)__float_as_int(p1.x) << 5) + li];
        float2 f0 = __half22float2(*(__half2*)&u0);
        float2 f1 = __half22float2(*(__half2*)&u1);
        acc0 += cf0 * f0.x; acc1 += cf0 * f0.y;
        acc0 += cf1 * f1.x; acc1 += cf1 * f1.y;
    }
    acc0 += __shfl_xor(acc0, 32);
    acc1 += __shfl_xor(acc1, 32);
    if (half == 0) {
        float2* o = (float2*)(out + (size_t)n * D);
        o[li] = make_float2(acc0, acc1);
    }
}

extern "C" void kernel_launch(void* const* d_in, const int* in_sizes, int n_in,
                              void* d_out, int out_size, void* d_ws, size_t ws_size,
                              hipStream_t stream)
{
    const float* x  = (const float*)d_in[0];
    const int*   ei = (const int*)d_in[1];
    const float* W  = (const float*)d_in[2];
    const float* a  = (const float*)d_in[3];
    float*       out = (float*)d_out;
    int N = in_sizes[0] / D;
    int E = in_sizes[1] / 2;
    const int* row = ei;
    const int* col = ei + E;

    int NB2  = (N + 255) / 256;          // 391 chunks (<= 512 for N<=131072)
    int NPAD = NB2 * 256;                // 100096

    // workspace layout: every array 256B-aligned (xh row alignment critical)
    uintptr_t wp = (uintptr_t)d_ws;
    auto alloc = [&wp](size_t bytes) -> void* {
        wp = (wp + 255) & ~(uintptr_t)255;
        void* p = (void*)wp;
        wp += bytes;
        return p;
    };
    __half* xh     = (__half*)alloc((size_t)N * D * 2);
    float2* ssrc   = (float2*)alloc((size_t)N * sizeof(float2));
    float2* sdst   = (float2*)alloc((size_t)N * sizeof(float2));
    float*  rowsum = (float*)alloc((size_t)NPAD * 2 * sizeof(float));
    int*    cntb   = (int*)alloc((size_t)NPAD * sizeof(int));     // contiguous
    float2* invrs  = (float2*)alloc((size_t)NPAD * sizeof(float2));
    int*    offs   = (int*)alloc((size_t)NPAD * sizeof(int));
    int*    bsum   = (int*)alloc(512 * sizeof(int));
    float2* pairs  = (float2*)alloc((size_t)E * sizeof(float2));

    // zero region = [rowsum, cntb + NPAD) — both 256B-aligned, int4-writable
    size_t zbytes  = (size_t)((char*)cntb - (char*)rowsum) + (size_t)NPAD * 4;
    int    zwords4 = (int)(zbytes / 16);
    int    ZBLK    = (zwords4 + 255) / 256;

    int EB = (E + 255) / 256;

    k_scores<<<ZBLK + (N + 3) / 4, 256, 0, stream>>>(
        x, W, a, ssrc, sdst, xh, (int4*)rowsum, zwords4, ZBLK, N);
    k_edge1<<<EB, 256, 0, stream>>>(row, col, ssrc, sdst, rowsum, cntb, E);
    k_scan_a<<<NB2, 256, 0, stream>>>(cntb, (const float2*)rowsum, offs, bsum, invrs);
    k_scan_b<<<1, 512, 0, stream>>>(bsum, NB2);
    k_edge2<<<EB, 256, 0, stream>>>(row, col, ssrc, sdst, invrs, bsum, offs, pairs, E);
    k_gather<<<(N + 3) / 4, 256, 0, stream>>>(
        (const unsigned*)xh, pairs, offs, cntb, bsum, out, N);
}